// Round 14
// baseline (428.186 us; speedup 1.0000x reference)
//
#include <hip/hip_runtime.h>
#include <hip/hip_bf16.h>
#include <stdint.h>
#include <type_traits>

typedef unsigned short u16;
typedef __bf16 bf16x8 __attribute__((ext_vector_type(8)));
typedef float f32x4 __attribute__((ext_vector_type(4)));

#define M_TOT 8192   // B*S
#define N_TOT 4096   // reduction dim
#define K_TOT 4096   // output dim
#define BM 256
#define BN 256
#define BK 64
#define NT 64        // N_TOT / BK

// LDS holds A ONLY: [slot][2 halves][128 rows][64 cols] bf16 = 64 KiB total
#define HALF_EL 8192       // 128 * 64
#define ASLOT_EL 16384     // 2 halves
#define ASLOT_BYTES 32768

#define CVT_BLOCKS 16384   // M_TOT*N_TOT/8/256
#define DEQ_BLOCKS 8192    // K_TOT*N_TOT/8/256

template <int V> using ic = std::integral_constant<int, V>;
template <bool V> using bc = std::integral_constant<bool, V>;

__device__ __forceinline__ u16 f2bf(float f) {
    union { float f; uint32_t u; } v; v.f = f;
    uint32_t u = v.u;
    return (u16)((u + 0x7fffu + ((u >> 16) & 1u)) >> 16);
}

// ---- fused pre-pass: blocks [0,CVT) convert x; [CVT, CVT+DEQ) dequantize W ----
__global__ __launch_bounds__(256) void prep_kernel(const float* __restrict__ x,
                                                   u16* __restrict__ xb,
                                                   const int* __restrict__ wq,
                                                   const float* __restrict__ scales,
                                                   const float* __restrict__ zeros,
                                                   const float* __restrict__ mu1,
                                                   const float* __restrict__ mu2,
                                                   u16* __restrict__ wb) {
    const int b = blockIdx.x;
    if (b < CVT_BLOCKS) {
        const int i = b * 256 + threadIdx.x;
        const float4* p = (const float4*)x + (size_t)i * 2;
        float4 v0 = p[0], v1 = p[1];
        uint4 o;
        o.x = (uint32_t)f2bf(v0.x) | ((uint32_t)f2bf(v0.y) << 16);
        o.y = (uint32_t)f2bf(v0.z) | ((uint32_t)f2bf(v0.w) << 16);
        o.z = (uint32_t)f2bf(v1.x) | ((uint32_t)f2bf(v1.y) << 16);
        o.w = (uint32_t)f2bf(v1.z) | ((uint32_t)f2bf(v1.w) << 16);
        *((uint4*)(xb + (size_t)i * 8)) = o;
    } else {
        const int i = (b - CVT_BLOCKS) * 256 + threadIdx.x;
        const int k  = i >> 9;
        const int n0 = (i & 511) << 3;
        const int g  = n0 >> 6;
        const float z  = zeros[k * 64 + g];
        const float sm = scales[k * 64 + g] * mu2[k];
        const int4* qp = (const int4*)(wq + (size_t)k * N_TOT + n0);
        int4 q0 = qp[0], q1 = qp[1];
        const float4* mp = (const float4*)(mu1 + n0);
        float4 u0 = mp[0], u1 = mp[1];
        uint4 o;
        o.x = (uint32_t)f2bf(((float)q0.x - z) * sm * u0.x) |
              ((uint32_t)f2bf(((float)q0.y - z) * sm * u0.y) << 16);
        o.y = (uint32_t)f2bf(((float)q0.z - z) * sm * u0.z) |
              ((uint32_t)f2bf(((float)q0.w - z) * sm * u0.w) << 16);
        o.z = (uint32_t)f2bf(((float)q1.x - z) * sm * u1.x) |
              ((uint32_t)f2bf(((float)q1.y - z) * sm * u1.y) << 16);
        o.w = (uint32_t)f2bf(((float)q1.z - z) * sm * u1.z) |
              ((uint32_t)f2bf(((float)q1.w - z) * sm * u1.w) << 16);
        *((uint4*)(wb + (size_t)k * N_TOT + n0)) = o;
    }
}

// ---- main GEMM: A via LDS (one-ahead), B DIRECT global->VGPR ------------------
// 8 waves (2M x 4N), per-wave out 128x64, BK=64. LDS = A only, double-buffered.
// Clusters: q0(afLo,bf0) q1(afLo,bf1) q2(afHi,bf0) q3(afHi,bf1).
// Loads (all one-ahead into just-dead reg groups; compiler emits counted
// vmcnt/lgkm waits at consumers — NO manual waits in the loop):
//   p1: afHi(t)      [LDS]                 (dead since prev q3; used q2)
//   p2: afLo(t+1)@S^1[LDS]                 (dead since q1;      used next q0)
//   p3: bf0(t+1) [4x global, pre-q3: bf0 died q2; used next q0]
//       bf1(t+1) [4x global, post-q3: bf1 died q3; used next q1]
// A stages (global_load_lds): p0: A1(t+1)->S^1 ; p2: A0(t+2)->S.
// DMA->ds_read safety: q0(t)'s automatic vmcnt (waits bf0(t), issued (t-1).p3)
// drains oldest-first ALL VMEM of tile t-1, incl. both A stages -> afHi(t)@p1
// and afLo'(t+1)@p2 read DMA-complete data. Prologue has the one manual vmcnt.
// WAR barriers (both kept from R11): p1-end barrier before stage A0(t+2)->S
// (afLo/bf0(t) reads serviced before each wave's q0 < its p1 barrier);
// p3-end barrier before next p0's stage A1(t+2)->S^1 (afHi(t) reads serviced
// before q2 < p3 barrier). sched_barrier(0) after each (rule #18).
// B direct pattern: lanes {l,l+16,l+32,l+48} read 64B contiguous of row l&15
// -> 16x64B requests/inst, L2/L3-served (wb 33MB L3-resident).
// LDS XOR swizzle on A (proven R2): phys col = logical ^ ((row&7)*8 elems).
__global__ __launch_bounds__(512, 2) void gemm_kernel(const u16* __restrict__ Xb,
                                                      const u16* __restrict__ Wb,
                                                      const float* __restrict__ bias,
                                                      float* __restrict__ out) {
    __shared__ __align__(16) u16 lds[2 * ASLOT_EL];   // 64 KiB, A only

    // XCD-bijective swizzle: nwg = 512, divisible by 8
    const int bid = blockIdx.x;
    const int cpx = gridDim.x >> 3;
    const int swz = (bid & 7) * cpx + (bid >> 3);
    const int bm = swz >> 4;    // 32 M-tiles
    const int bn = swz & 15;    // 16 out-tiles

    const int tid  = threadIdx.x;
    const int w    = tid >> 6;
    const int lane = tid & 63;
    const int wm = w >> 2, wn = w & 3;

    // A staging: lane l, issue i covers LDS row (w*16 + i*8 + (l>>3)), physical
    // col (l&7)*16B; global col pre-swizzled: ((l&7)^(l>>3))*8 elems.
    const int scol = (((lane & 7) ^ (lane >> 3)) << 3);
    const u16* aT = Xb + (size_t)(bm * BM + w * 16 + (lane >> 3)) * N_TOT + scol;

    u16* const sdA = &lds[w * 1024];

    auto gload = [](const u16* s, u16* d) {
        __builtin_amdgcn_global_load_lds(
            (const __attribute__((address_space(1))) uint32_t*)s,
            (__attribute__((address_space(3))) uint32_t*)d, 16, 0, 0);
    };
    auto stA = [&](auto SlC, auto Hc, auto Dc) {
        const u16* s = aT + (size_t)(Hc.value * 128) * N_TOT + Dc.value;
        u16* d = sdA + SlC.value * ASLOT_EL + Hc.value * HALF_EL;
        gload(s, d); gload(s + (size_t)8 * N_TOT, d + 512);
    };

    // A-fragment read offsets (bytes), toggling slot via ^= ASLOT_BYTES
    const int cc0 = (((lane >> 4) << 3)) ^ ((lane & 7) << 3);
    const int rA  = ((wm << 4) + (lane & 15)) << 6;
    int oAa = (rA + cc0) * 2;
    int oAb = (rA + (cc0 ^ 32)) * 2;
    const char* const ldsc = (const char*)lds;

    // B direct-load base pointers [nh][j2], at CURRENT tile; advance 64/tile.
    // lane reads row (bn*256 + nh*128 + j2*64 + wn*16 + (lane&15)),
    // k = t*64 + (lane>>4)*8 + ks*32  (8 bf16 = 16B per load).
    const u16* pB00 = Wb + (size_t)(bn * BN + wn * 16 + (lane & 15)) * N_TOT
                         + ((lane >> 4) << 3);
    const u16* pB01 = pB00 + (size_t)64 * N_TOT;
    const u16* pB10 = pB00 + (size_t)128 * N_TOT;
    const u16* pB11 = pB00 + (size_t)192 * N_TOT;

    f32x4 acc[2][2][4][2] = {};
    bf16x8 afLo[4][2], afHi[4][2];   // [j][ks]
    bf16x8 bf0[2][2], bf1[2][2];     // [j2][ks]

    auto rd_afLo_next = [&]() {   // A half0 of NEXT tile (other slot)
        const int xa = oAa ^ ASLOT_BYTES, xb2 = oAb ^ ASLOT_BYTES;
        #pragma unroll
        for (int j = 0; j < 4; ++j) {
            afLo[j][0] = *(const bf16x8*)(ldsc + xa + j * 4096);
            afLo[j][1] = *(const bf16x8*)(ldsc + xb2 + j * 4096);
        }
    };
    auto rd_afHi_cur = [&]() {    // A half1 of CURRENT tile
        #pragma unroll
        for (int j = 0; j < 4; ++j) {
            afHi[j][0] = *(const bf16x8*)(ldsc + oAa + 16384 + j * 4096);
            afHi[j][1] = *(const bf16x8*)(ldsc + oAb + 16384 + j * 4096);
        }
    };
    auto rd_bf0_next = [&]() {    // B half0 (nh=0) of NEXT tile: +64 elems
        #pragma unroll
        for (int ks = 0; ks < 2; ++ks) {
            bf0[0][ks] = *(const bf16x8*)(pB00 + 64 + ks * 32);
            bf0[1][ks] = *(const bf16x8*)(pB01 + 64 + ks * 32);
        }
    };
    auto rd_bf1_next = [&]() {    // B half1 (nh=1) of NEXT tile: +64 elems
        #pragma unroll
        for (int ks = 0; ks < 2; ++ks) {
            bf1[0][ks] = *(const bf16x8*)(pB10 + 64 + ks * 32);
            bf1[1][ks] = *(const bf16x8*)(pB11 + 64 + ks * 32);
        }
    };

    #define MFMA_CLUSTER(A, B, MH, NH)                                          \
        __builtin_amdgcn_s_setprio(1);                                          \
        _Pragma("unroll")                                                       \
        for (int ks = 0; ks < 2; ++ks)                                          \
            _Pragma("unroll")                                                   \
            for (int j = 0; j < 4; ++j)                                         \
                _Pragma("unroll")                                               \
                for (int j2 = 0; j2 < 2; ++j2)                                  \
                    acc[MH][NH][j][j2] = __builtin_amdgcn_mfma_f32_16x16x32_bf16(\
                        A[j][ks], B[j2][ks], acc[MH][NH][j][j2], 0, 0, 0);      \
        __builtin_amdgcn_s_setprio(0);

    // one K-tile. St0: stage A1(t+1)->S^1 @p0. St2: stage A0(t+2)->S @p2.
    // RdN: one-ahead reads of tile t+1 (afLo', bf0', bf1').
    auto ktile = [&](auto SlC, auto St0, auto St2, auto RdN, auto D0, auto D1) {
        constexpr int SL = SlC.value;
        // ---- p0 ----
        if constexpr (St0.value) stA(ic<SL ^ 1>{}, ic<1>{}, D0);
        MFMA_CLUSTER(afLo, bf0, 0, 0)
        // ---- p1 ----
        rd_afHi_cur();
        MFMA_CLUSTER(afLo, bf1, 0, 1)
        __builtin_amdgcn_s_barrier();
        __builtin_amdgcn_sched_barrier(0);
        // ---- p2 ----
        if constexpr (RdN.value) rd_afLo_next();
        if constexpr (St2.value) stA(SlC, ic<0>{}, D1);
        MFMA_CLUSTER(afHi, bf0, 1, 0)
        // ---- p3 ----
        if constexpr (RdN.value) rd_bf0_next();   // bf0 died at q2
        MFMA_CLUSTER(afHi, bf1, 1, 1)
        if constexpr (RdN.value) rd_bf1_next();   // bf1 died at q3
        __builtin_amdgcn_s_barrier();
        __builtin_amdgcn_sched_barrier(0);
        // advance to next tile
        oAa ^= ASLOT_BYTES; oAb ^= ASLOT_BYTES;
        pB00 += 64; pB01 += 64; pB10 += 64; pB11 += 64;
    };

    // prologue: stage A0(0),A1(0)->slot0, A0(1)->slot1; load bf0(0),bf1(0).
    // vmcnt(10) waits the oldest 4 gloads (= tile0's A halves) before the
    // afLo(0) ds_read; everything else drains via q0(0)'s automatic wait.
    stA(ic<0>{}, ic<0>{}, ic<0>{});
    stA(ic<0>{}, ic<1>{}, ic<0>{});
    stA(ic<1>{}, ic<0>{}, ic<BK>{});
    #pragma unroll
    for (int ks = 0; ks < 2; ++ks) {
        bf0[0][ks] = *(const bf16x8*)(pB00 + ks * 32);
        bf0[1][ks] = *(const bf16x8*)(pB01 + ks * 32);
    }
    #pragma unroll
    for (int ks = 0; ks < 2; ++ks) {
        bf1[0][ks] = *(const bf16x8*)(pB10 + ks * 32);
        bf1[1][ks] = *(const bf16x8*)(pB11 + ks * 32);
    }
    asm volatile("s_waitcnt vmcnt(10)" ::: "memory");
    __builtin_amdgcn_s_barrier();
    __builtin_amdgcn_sched_barrier(0);
    {   // initial afLo(0) from slot 0
        #pragma unroll
        for (int j = 0; j < 4; ++j) {
            afLo[j][0] = *(const bf16x8*)(ldsc + oAa + j * 4096);
            afLo[j][1] = *(const bf16x8*)(ldsc + oAb + j * 4096);
        }
    }

    // steady: 31 pairs = tiles 0..61 (aT at even tile of pair)
    for (int it = 0; it < 31; ++it) {
        ktile(ic<0>{}, bc<true>{}, bc<true>{}, bc<true>{}, ic<BK>{},     ic<2 * BK>{});
        ktile(ic<1>{}, bc<true>{}, bc<true>{}, bc<true>{}, ic<2 * BK>{}, ic<3 * BK>{});
        aT += 2 * BK;
    }
    // tile 62: stage A1(63) only; one-ahead reads for 63
    ktile(ic<0>{}, bc<true>{}, bc<false>{}, bc<true>{}, ic<BK>{}, ic<0>{});
    // tile 63: nothing ahead
    ktile(ic<1>{}, bc<false>{}, bc<false>{}, bc<false>{}, ic<0>{}, ic<0>{});

    #undef MFMA_CLUSTER

    // epilogue: C/D layout col = lane&15 (out-dim), row = (lane>>4)*4 + rr (M)
    #pragma unroll
    for (int mh_ = 0; mh_ < 2; ++mh_)
        #pragma unroll
        for (int j = 0; j < 4; ++j)
            #pragma unroll
            for (int rr = 0; rr < 4; ++rr) {
                const int row = bm * BM + mh_ * 128 + j * 32 + wm * 16 + ((lane >> 4) << 2) + rr;
                float* orow = out + (size_t)row * K_TOT;
                #pragma unroll
                for (int nh_ = 0; nh_ < 2; ++nh_)
                    #pragma unroll
                    for (int j2 = 0; j2 < 2; ++j2) {
                        const int col = bn * BN + nh_ * 128 + j2 * 64 + wn * 16 + (lane & 15);
                        orow[col] = acc[mh_][nh_][j][j2][rr] + bias[col];
                    }
            }
}

extern "C" void kernel_launch(void* const* d_in, const int* in_sizes, int n_in,
                              void* d_out, int out_size, void* d_ws, size_t ws_size,
                              hipStream_t stream) {
    const float* x      = (const float*)d_in[0];
    const float* scales = (const float*)d_in[1];
    const float* zeros  = (const float*)d_in[2];
    const float* mu1    = (const float*)d_in[3];
    const float* mu2    = (const float*)d_in[4];
    const float* bias   = (const float*)d_in[5];
    const int*   wq     = (const int*)d_in[6];
    float* out = (float*)d_out;

    u16* xb = (u16*)d_ws;                                 // 64 MiB
    u16* wb = (u16*)d_ws + (size_t)M_TOT * N_TOT;         // 32 MiB

    prep_kernel<<<CVT_BLOCKS + DEQ_BLOCKS, 256, 0, stream>>>(
        x, xb, wq, scales, zeros, mu1, mu2, wb);
    gemm_kernel<<<(M_TOT / BM) * (K_TOT / BN), 512, 0, stream>>>(xb, wb, bias, out);
}

// Round 15
// 277.162 us; speedup vs baseline: 1.5449x; 1.5449x over previous
//
#include <hip/hip_runtime.h>
#include <hip/hip_bf16.h>
#include <stdint.h>
#include <type_traits>

typedef unsigned short u16;
typedef __bf16 bf16x8 __attribute__((ext_vector_type(8)));
typedef float f32x4 __attribute__((ext_vector_type(4)));

#define M_TOT 8192   // B*S
#define N_TOT 4096   // reduction dim
#define K_TOT 4096   // output dim
#define BM 256
#define BN 256
#define BK 64
#define NT 64        // N_TOT / BK

// LDS geometry in u16 elements: [slot][A:2 halves | B:2 halves][128][64]
#define HALF_EL 8192     // 128 rows * 64 cols
#define B_OFF   16384
#define SLOT_EL 32768    // 64 KiB per slot
#define SLOT_BYTES 65536

#define CVT_BLOCKS 16384   // M_TOT*N_TOT/8/256
#define DEQ_BLOCKS 8192    // K_TOT*N_TOT/8/256

template <int V> using ic = std::integral_constant<int, V>;
template <bool V> using bc = std::integral_constant<bool, V>;

__device__ __forceinline__ u16 f2bf(float f) {
    union { float f; uint32_t u; } v; v.f = f;
    uint32_t u = v.u;
    return (u16)((u + 0x7fffu + ((u >> 16) & 1u)) >> 16);
}

// ---- fused pre-pass: blocks [0,CVT) convert x; [CVT, CVT+DEQ) dequantize W ----
__global__ __launch_bounds__(256) void prep_kernel(const float* __restrict__ x,
                                                   u16* __restrict__ xb,
                                                   const int* __restrict__ wq,
                                                   const float* __restrict__ scales,
                                                   const float* __restrict__ zeros,
                                                   const float* __restrict__ mu1,
                                                   const float* __restrict__ mu2,
                                                   u16* __restrict__ wb) {
    const int b = blockIdx.x;
    if (b < CVT_BLOCKS) {
        const int i = b * 256 + threadIdx.x;
        const float4* p = (const float4*)x + (size_t)i * 2;
        float4 v0 = p[0], v1 = p[1];
        uint4 o;
        o.x = (uint32_t)f2bf(v0.x) | ((uint32_t)f2bf(v0.y) << 16);
        o.y = (uint32_t)f2bf(v0.z) | ((uint32_t)f2bf(v0.w) << 16);
        o.z = (uint32_t)f2bf(v1.x) | ((uint32_t)f2bf(v1.y) << 16);
        o.w = (uint32_t)f2bf(v1.z) | ((uint32_t)f2bf(v1.w) << 16);
        *((uint4*)(xb + (size_t)i * 8)) = o;
    } else {
        const int i = (b - CVT_BLOCKS) * 256 + threadIdx.x;
        const int k  = i >> 9;
        const int n0 = (i & 511) << 3;
        const int g  = n0 >> 6;
        const float z  = zeros[k * 64 + g];
        const float sm = scales[k * 64 + g] * mu2[k];
        const int4* qp = (const int4*)(wq + (size_t)k * N_TOT + n0);
        int4 q0 = qp[0], q1 = qp[1];
        const float4* mp = (const float4*)(mu1 + n0);
        float4 u0 = mp[0], u1 = mp[1];
        uint4 o;
        o.x = (uint32_t)f2bf(((float)q0.x - z) * sm * u0.x) |
              ((uint32_t)f2bf(((float)q0.y - z) * sm * u0.y) << 16);
        o.y = (uint32_t)f2bf(((float)q0.z - z) * sm * u0.z) |
              ((uint32_t)f2bf(((float)q0.w - z) * sm * u0.w) << 16);
        o.z = (uint32_t)f2bf(((float)q1.x - z) * sm * u1.x) |
              ((uint32_t)f2bf(((float)q1.y - z) * sm * u1.y) << 16);
        o.w = (uint32_t)f2bf(((float)q1.z - z) * sm * u1.z) |
              ((uint32_t)f2bf(((float)q1.w - z) * sm * u1.w) << 16);
        *((uint4*)(wb + (size_t)k * N_TOT + n0)) = o;
    }
}

// ---- main GEMM: R13 one-ahead feed + batched p0 stage, ONE wait/tile ----------
// 8 waves (2M x 4N), per-wave out 128x64, BK=64, double-buffered LDS.
// Quadrants: q0=(A0,B0) q1=(A0,B1) q2=(A1,B1) q3=(A1,B0).
// ONE-AHEAD reads (compiler emits counted lgkm waits at consumers; NO explicit
// lgkm anywhere):
//   p0: bf1(t); stage BURST: A1,B1(t+1)->S^1 + A0,B0(t+2)->S (8 gloads);
//       MFMA q0(afLo,bf0)
//   p1: afHi(t); MFMA q1(afLo,bf1); barrier; sched_barrier  [no vmcnt]
//   p2: afLo(t+1)@S^1; MFMA q2(afHi,bf1)
//   p3: MFMA q3(afHi,bf0); bf0(t+1)@S^1; vmcnt(0); barrier; sched_barrier
// vmcnt: only p3-end vmcnt(0) — drains the p0 burst issued ~3 clusters
// (~1800cy > 900 HBM) earlier; every tile starts with an empty VMEM pipe,
// so all staged data for tile t+1 (A1B1 from t.p0; A0B0 from (t-1).p0) is
// LDS-resident at the p3-end barrier.
// WAR legality of the p0 burst:
//   S^1.A1/B1(t+1) target: last reads afHi/bf1(t-1) consumed by t-1's q2/q3,
//     before t-1's p3-end barrier.
//   S.A0/B0(t+2) target: last reads were rd_afLo_next/rd_bf0_next issued at
//     t-1.p2/p3 (serviced within the t-1.p3 window); stage-writes land >=900cy
//     after t.p0 issue, i.e. >= one barrier + one cluster after those reads
//     entered the LDS queue (FIFO service) — no overlap.
// Race-sensitive reads follow the asm-"memory" vmcnt/barrier -> cannot hoist
// (sched_barrier(0) after each barrier, rule #18).
// LDS XOR swizzle (proven R2): physical col = logical ^ ((row&7)*8 elems).
__global__ __launch_bounds__(512, 2) void gemm_kernel(const u16* __restrict__ Xb,
                                                      const u16* __restrict__ Wb,
                                                      const float* __restrict__ bias,
                                                      float* __restrict__ out) {
    __shared__ __align__(16) u16 lds[2 * SLOT_EL];   // 128 KiB

    // XCD-bijective swizzle: nwg = 512, divisible by 8
    const int bid = blockIdx.x;
    const int cpx = gridDim.x >> 3;
    const int swz = (bid & 7) * cpx + (bid >> 3);
    const int bm = swz >> 4;    // 32 M-tiles
    const int bn = swz & 15;    // 16 out-tiles

    const int tid  = threadIdx.x;
    const int w    = tid >> 6;
    const int lane = tid & 63;
    const int wm = w >> 2, wn = w & 3;

    // staging: lane l, issue i covers LDS row (w*16 + i*8 + (l>>3)), physical
    // col (l&7)*16B; global col pre-swizzled: ((l&7)^(l>>3))*8 elems.
    const int scol = (((lane & 7) ^ (lane >> 3)) << 3);
    const u16* aT = Xb + (size_t)(bm * BM + w * 16 + (lane >> 3)) * N_TOT + scol;
    const u16* bT = Wb + (size_t)(bn * BN + w * 16 + (lane >> 3)) * N_TOT + scol;

    u16* const sdA = &lds[w * 1024];
    u16* const sdB = &lds[B_OFF + w * 1024];

    auto gload = [](const u16* s, u16* d) {
        __builtin_amdgcn_global_load_lds(
            (const __attribute__((address_space(1))) uint32_t*)s,
            (__attribute__((address_space(3))) uint32_t*)d, 16, 0, 0);
    };
    auto stA = [&](auto SlC, auto Hc, auto Dc) {
        const u16* s = aT + (size_t)(Hc.value * 128) * N_TOT + Dc.value;
        u16* d = sdA + SlC.value * SLOT_EL + Hc.value * HALF_EL;
        gload(s, d); gload(s + (size_t)8 * N_TOT, d + 512);
    };
    auto stB = [&](auto SlC, auto Hc, auto Dc) {
        const u16* s = bT + (size_t)(Hc.value * 128) * N_TOT + Dc.value;
        u16* d = sdB + SlC.value * SLOT_EL + Hc.value * HALF_EL;
        gload(s, d); gload(s + (size_t)8 * N_TOT, d + 512);
    };

    // toggling LDS read byte-offsets (current slot); ks0/ks1 variants
    const int cc0 = (((lane >> 4) << 3)) ^ ((lane & 7) << 3);
    const int rA  = ((wm << 4) + (lane & 15)) << 6;
    const int rB  = ((wn << 4) + (lane & 15)) << 6;
    int oAa = (rA + cc0) * 2;
    int oAb = (rA + (cc0 ^ 32)) * 2;
    int oBa = (B_OFF + rB + cc0) * 2;
    int oBb = (B_OFF + rB + (cc0 ^ 32)) * 2;
    const char* const ldsc = (const char*)lds;

    f32x4 acc[2][2][4][2] = {};
    bf16x8 afLo[4][2], afHi[4][2];   // [j][ks]
    bf16x8 bf0[2][2], bf1[2][2];     // [j2][ks]

    auto rd_afLo_next = [&]() {   // A half0 of NEXT tile (other slot)
        const int xa = oAa ^ SLOT_BYTES, xb2 = oAb ^ SLOT_BYTES;
        #pragma unroll
        for (int j = 0; j < 4; ++j) {
            afLo[j][0] = *(const bf16x8*)(ldsc + xa + j * 4096);
            afLo[j][1] = *(const bf16x8*)(ldsc + xb2 + j * 4096);
        }
    };
    auto rd_bf0_next = [&]() {    // B half0 of NEXT tile (other slot)
        const int xa = oBa ^ SLOT_BYTES, xb2 = oBb ^ SLOT_BYTES;
        #pragma unroll
        for (int j2 = 0; j2 < 2; ++j2) {
            bf0[j2][0] = *(const bf16x8*)(ldsc + xa + j2 * 8192);
            bf0[j2][1] = *(const bf16x8*)(ldsc + xb2 + j2 * 8192);
        }
    };
    auto rd_afHi_cur = [&]() {    // A half1 of CURRENT tile
        #pragma unroll
        for (int j = 0; j < 4; ++j) {
            afHi[j][0] = *(const bf16x8*)(ldsc + oAa + 16384 + j * 4096);
            afHi[j][1] = *(const bf16x8*)(ldsc + oAb + 16384 + j * 4096);
        }
    };
    auto rd_bf1_cur = [&]() {     // B half1 of CURRENT tile
        #pragma unroll
        for (int j2 = 0; j2 < 2; ++j2) {
            bf1[j2][0] = *(const bf16x8*)(ldsc + oBa + 16384 + j2 * 8192);
            bf1[j2][1] = *(const bf16x8*)(ldsc + oBb + 16384 + j2 * 8192);
        }
    };

    #define MFMA_CLUSTER(A, B, MH, NH)                                          \
        __builtin_amdgcn_s_setprio(1);                                          \
        _Pragma("unroll")                                                       \
        for (int ks = 0; ks < 2; ++ks)                                          \
            _Pragma("unroll")                                                   \
            for (int j = 0; j < 4; ++j)                                         \
                _Pragma("unroll")                                               \
                for (int j2 = 0; j2 < 2; ++j2)                                  \
                    acc[MH][NH][j][j2] = __builtin_amdgcn_mfma_f32_16x16x32_bf16(\
                        A[j][ks], B[j2][ks], acc[MH][NH][j][j2], 0, 0, 0);      \
        __builtin_amdgcn_s_setprio(0);

    // one K-tile. St0: stage A1B1(t+1)->S^1 @p0. St2: stage A0B0(t+2)->S @p0.
    // RdN: one-ahead reads of tile t+1. Vw: do the p3-end vmcnt(0).
    auto ktile = [&](auto SlC, auto St0, auto St2, auto RdN, auto Vw,
                     auto D0, auto D1) {
        constexpr int SL = SlC.value;
        // ---- p0: batched stage burst + q0 ----
        rd_bf1_cur();
        if constexpr (St0.value) { stA(ic<SL ^ 1>{}, ic<1>{}, D0);
                                   stB(ic<SL ^ 1>{}, ic<1>{}, D0); }
        if constexpr (St2.value) { stA(SlC, ic<0>{}, D1);
                                   stB(SlC, ic<0>{}, D1); }
        MFMA_CLUSTER(afLo, bf0, 0, 0)
        // ---- p1 ----
        rd_afHi_cur();
        MFMA_CLUSTER(afLo, bf1, 0, 1)
        __builtin_amdgcn_s_barrier();
        __builtin_amdgcn_sched_barrier(0);
        // ---- p2 ----
        if constexpr (RdN.value) rd_afLo_next();
        MFMA_CLUSTER(afHi, bf1, 1, 1)
        // ---- p3 ----
        MFMA_CLUSTER(afHi, bf0, 1, 0)
        if constexpr (RdN.value) rd_bf0_next();
        if constexpr (Vw.value) asm volatile("s_waitcnt vmcnt(0)" ::: "memory");
        __builtin_amdgcn_s_barrier();
        __builtin_amdgcn_sched_barrier(0);
        // toggle read bases to the other slot
        oAa ^= SLOT_BYTES; oAb ^= SLOT_BYTES; oBa ^= SLOT_BYTES; oBb ^= SLOT_BYTES;
    };

    // prologue: stage tile0 full (8) + A0,B0(tile1) (4); vmcnt(0); barrier;
    // read tile0's q0 fragments. (Every tile thereafter starts pipe-clean.)
    stA(ic<0>{}, ic<0>{}, ic<0>{});  stB(ic<0>{}, ic<0>{}, ic<0>{});
    stA(ic<0>{}, ic<1>{}, ic<0>{});  stB(ic<0>{}, ic<1>{}, ic<0>{});
    stA(ic<1>{}, ic<0>{}, ic<BK>{}); stB(ic<1>{}, ic<0>{}, ic<BK>{});
    asm volatile("s_waitcnt vmcnt(0)" ::: "memory");
    __builtin_amdgcn_s_barrier();
    __builtin_amdgcn_sched_barrier(0);
    {   // initial q0 fragments from slot 0 (bases currently at slot 0)
        #pragma unroll
        for (int j = 0; j < 4; ++j) {
            afLo[j][0] = *(const bf16x8*)(ldsc + oAa + j * 4096);
            afLo[j][1] = *(const bf16x8*)(ldsc + oAb + j * 4096);
        }
        #pragma unroll
        for (int j2 = 0; j2 < 2; ++j2) {
            bf0[j2][0] = *(const bf16x8*)(ldsc + oBa + j2 * 8192);
            bf0[j2][1] = *(const bf16x8*)(ldsc + oBb + j2 * 8192);
        }
    }

    // steady: 31 pairs = tiles 0..61 (aT/bT at even tile of pair)
    for (int it = 0; it < 31; ++it) {
        ktile(ic<0>{}, bc<true>{}, bc<true>{}, bc<true>{}, bc<true>{},
              ic<BK>{},     ic<2 * BK>{});
        ktile(ic<1>{}, bc<true>{}, bc<true>{}, bc<true>{}, bc<true>{},
              ic<2 * BK>{}, ic<3 * BK>{});
        aT += 2 * BK;
        bT += 2 * BK;
    }
    // tile 62: stage A1B1(63) only; p3-end vmcnt(0) drains it for tile 63.
    ktile(ic<0>{}, bc<true>{}, bc<false>{}, bc<true>{}, bc<true>{},
          ic<BK>{}, ic<0>{});
    // tile 63: no stages, no ahead-reads, pipe already clean
    ktile(ic<1>{}, bc<false>{}, bc<false>{}, bc<false>{}, bc<false>{},
          ic<0>{}, ic<0>{});

    #undef MFMA_CLUSTER

    // epilogue: C/D layout col = lane&15 (out-dim), row = (lane>>4)*4 + rr (M)
    #pragma unroll
    for (int mh_ = 0; mh_ < 2; ++mh_)
        #pragma unroll
        for (int j = 0; j < 4; ++j)
            #pragma unroll
            for (int rr = 0; rr < 4; ++rr) {
                const int row = bm * BM + mh_ * 128 + j * 32 + wm * 16 + ((lane >> 4) << 2) + rr;
                float* orow = out + (size_t)row * K_TOT;
                #pragma unroll
                for (int nh_ = 0; nh_ < 2; ++nh_)
                    #pragma unroll
                    for (int j2 = 0; j2 < 2; ++j2) {
                        const int col = bn * BN + nh_ * 128 + j2 * 64 + wn * 16 + (lane & 15);
                        orow[col] = acc[mh_][nh_][j][j2][rr] + bias[col];
                    }
            }
}

extern "C" void kernel_launch(void* const* d_in, const int* in_sizes, int n_in,
                              void* d_out, int out_size, void* d_ws, size_t ws_size,
                              hipStream_t stream) {
    const float* x      = (const float*)d_in[0];
    const float* scales = (const float*)d_in[1];
    const float* zeros  = (const float*)d_in[2];
    const float* mu1    = (const float*)d_in[3];
    const float* mu2    = (const float*)d_in[4];
    const float* bias   = (const float*)d_in[5];
    const int*   wq     = (const int*)d_in[6];
    float* out = (float*)d_out;

    u16* xb = (u16*)d_ws;                                 // 64 MiB
    u16* wb = (u16*)d_ws + (size_t)M_TOT * N_TOT;         // 32 MiB

    prep_kernel<<<CVT_BLOCKS + DEQ_BLOCKS, 256, 0, stream>>>(
        x, xb, wq, scales, zeros, mu1, mu2, wb);
    gemm_kernel<<<(M_TOT / BM) * (K_TOT / BN), 512, 0, stream>>>(xb, wb, bias, out);
}

// Round 16
// 261.748 us; speedup vs baseline: 1.6359x; 1.0589x over previous
//
#include <hip/hip_runtime.h>
#include <hip/hip_bf16.h>
#include <stdint.h>
#include <type_traits>

typedef unsigned short u16;
typedef __bf16 bf16x8 __attribute__((ext_vector_type(8)));
typedef float f32x4 __attribute__((ext_vector_type(4)));

#define M_TOT 8192   // B*S
#define N_TOT 4096   // reduction dim
#define K_TOT 4096   // output dim
#define BM 256
#define BN 256
#define BK 64
#define NT 64        // N_TOT / BK

// LDS geometry in u16 elements: [slot][A:2 halves | B:2 halves][128][64]
#define HALF_EL 8192     // 128 rows * 64 cols
#define B_OFF   16384
#define SLOT_EL 32768    // 64 KiB per slot
#define SLOT_BYTES 65536

#define CVT_BLOCKS 16384   // M_TOT*N_TOT/8/256
#define DEQ_BLOCKS 8192    // K_TOT*N_TOT/8/256

template <int V> using ic = std::integral_constant<int, V>;
template <bool V> using bc = std::integral_constant<bool, V>;

__device__ __forceinline__ u16 f2bf(float f) {
    union { float f; uint32_t u; } v; v.f = f;
    uint32_t u = v.u;
    return (u16)((u + 0x7fffu + ((u >> 16) & 1u)) >> 16);
}

// ---- fused pre-pass: blocks [0,CVT) convert x; [CVT, CVT+DEQ) dequantize W ----
__global__ __launch_bounds__(256) void prep_kernel(const float* __restrict__ x,
                                                   u16* __restrict__ xb,
                                                   const int* __restrict__ wq,
                                                   const float* __restrict__ scales,
                                                   const float* __restrict__ zeros,
                                                   const float* __restrict__ mu1,
                                                   const float* __restrict__ mu2,
                                                   u16* __restrict__ wb) {
    const int b = blockIdx.x;
    if (b < CVT_BLOCKS) {
        const int i = b * 256 + threadIdx.x;
        const float4* p = (const float4*)x + (size_t)i * 2;
        float4 v0 = p[0], v1 = p[1];
        uint4 o;
        o.x = (uint32_t)f2bf(v0.x) | ((uint32_t)f2bf(v0.y) << 16);
        o.y = (uint32_t)f2bf(v0.z) | ((uint32_t)f2bf(v0.w) << 16);
        o.z = (uint32_t)f2bf(v1.x) | ((uint32_t)f2bf(v1.y) << 16);
        o.w = (uint32_t)f2bf(v1.z) | ((uint32_t)f2bf(v1.w) << 16);
        *((uint4*)(xb + (size_t)i * 8)) = o;
    } else {
        const int i = (b - CVT_BLOCKS) * 256 + threadIdx.x;
        const int k  = i >> 9;
        const int n0 = (i & 511) << 3;
        const int g  = n0 >> 6;
        const float z  = zeros[k * 64 + g];
        const float sm = scales[k * 64 + g] * mu2[k];
        const int4* qp = (const int4*)(wq + (size_t)k * N_TOT + n0);
        int4 q0 = qp[0], q1 = qp[1];
        const float4* mp = (const float4*)(mu1 + n0);
        float4 u0 = mp[0], u1 = mp[1];
        uint4 o;
        o.x = (uint32_t)f2bf(((float)q0.x - z) * sm * u0.x) |
              ((uint32_t)f2bf(((float)q0.y - z) * sm * u0.y) << 16);
        o.y = (uint32_t)f2bf(((float)q0.z - z) * sm * u0.z) |
              ((uint32_t)f2bf(((float)q0.w - z) * sm * u0.w) << 16);
        o.z = (uint32_t)f2bf(((float)q1.x - z) * sm * u1.x) |
              ((uint32_t)f2bf(((float)q1.y - z) * sm * u1.y) << 16);
        o.w = (uint32_t)f2bf(((float)q1.z - z) * sm * u1.z) |
              ((uint32_t)f2bf(((float)q1.w - z) * sm * u1.w) << 16);
        *((uint4*)(wb + (size_t)k * N_TOT + n0)) = o;
    }
}

// ---- main GEMM: R13 one-ahead feed, BALANCED 4-phase stage->wait flight -------
// 8 waves (2M x 4N), per-wave out 128x64, BK=64, double-buffered LDS.
// Quadrants: q0=(A0,B0) q1=(A0,B1) q2=(A1,B1) q3=(A1,B0).
// ONE-AHEAD frag reads (compiler places counted lgkm at consumers; NO explicit
// lgkm):  p0: bf1(t) | p1: afHi(t) | p2: afLo(t+1)@S^1 | p3(post-q3): bf0(t+1).
// STAGING — tile t stages ALL of t+2 into its own slot S (parity(t+2)=parity(t)):
//   p1: A0,B0(t+2)->S   [S.A0/B0 dead since t-1.p2/p3 ahead-reads]
//   p3: A1,B1(t+2)->S   [S.A1/B1 dead since t.p1/p0 reads; p1-end barrier
//                        globally precedes p3 -> no wave's read outstanding]
// WAITS — both vmcnt(8), each draining loads staged 4 PHASES (~1300cy) earlier
// (R13's p3 wait was 3 clusters ~800cy < 900cy HBM latency = the stall):
//   t.p1-end: outstanding {A0B0(t+1),A1B1(t+1),A0B0(t+2)}=12 -> vmcnt(8)
//     drains A0B0(t+1) [staged t-1.p1], needed by p2's afLo' read.
//   t.p3-end: outstanding {A1B1(t+1),A0B0(t+2),A1B1(t+2)}=12 -> vmcnt(8)
//     drains A1B1(t+1) [staged t-1.p3], needed by t+1.p0/p1 reads.
// Race-sensitive reads follow asm-"memory" vmcnt+barrier+sched_barrier (rule #18).
// LDS XOR swizzle (proven R2): physical col = logical ^ ((row&7)*8 elems).
__global__ __launch_bounds__(512, 2) void gemm_kernel(const u16* __restrict__ Xb,
                                                      const u16* __restrict__ Wb,
                                                      const float* __restrict__ bias,
                                                      float* __restrict__ out) {
    __shared__ __align__(16) u16 lds[2 * SLOT_EL];   // 128 KiB

    // XCD-bijective swizzle: nwg = 512, divisible by 8
    const int bid = blockIdx.x;
    const int cpx = gridDim.x >> 3;
    const int swz = (bid & 7) * cpx + (bid >> 3);
    const int bm = swz >> 4;    // 32 M-tiles
    const int bn = swz & 15;    // 16 out-tiles

    const int tid  = threadIdx.x;
    const int w    = tid >> 6;
    const int lane = tid & 63;
    const int wm = w >> 2, wn = w & 3;

    // staging: lane l, issue i covers LDS row (w*16 + i*8 + (l>>3)), physical
    // col (l&7)*16B; global col pre-swizzled: ((l&7)^(l>>3))*8 elems.
    const int scol = (((lane & 7) ^ (lane >> 3)) << 3);
    const u16* aT = Xb + (size_t)(bm * BM + w * 16 + (lane >> 3)) * N_TOT + scol;
    const u16* bT = Wb + (size_t)(bn * BN + w * 16 + (lane >> 3)) * N_TOT + scol;

    u16* const sdA = &lds[w * 1024];
    u16* const sdB = &lds[B_OFF + w * 1024];

    auto gload = [](const u16* s, u16* d) {
        __builtin_amdgcn_global_load_lds(
            (const __attribute__((address_space(1))) uint32_t*)s,
            (__attribute__((address_space(3))) uint32_t*)d, 16, 0, 0);
    };
    auto stA = [&](auto SlC, auto Hc, auto Dc) {
        const u16* s = aT + (size_t)(Hc.value * 128) * N_TOT + Dc.value;
        u16* d = sdA + SlC.value * SLOT_EL + Hc.value * HALF_EL;
        gload(s, d); gload(s + (size_t)8 * N_TOT, d + 512);
    };
    auto stB = [&](auto SlC, auto Hc, auto Dc) {
        const u16* s = bT + (size_t)(Hc.value * 128) * N_TOT + Dc.value;
        u16* d = sdB + SlC.value * SLOT_EL + Hc.value * HALF_EL;
        gload(s, d); gload(s + (size_t)8 * N_TOT, d + 512);
    };

    // toggling LDS read byte-offsets (current slot); ks0/ks1 variants
    const int cc0 = (((lane >> 4) << 3)) ^ ((lane & 7) << 3);
    const int rA  = ((wm << 4) + (lane & 15)) << 6;
    const int rB  = ((wn << 4) + (lane & 15)) << 6;
    int oAa = (rA + cc0) * 2;
    int oAb = (rA + (cc0 ^ 32)) * 2;
    int oBa = (B_OFF + rB + cc0) * 2;
    int oBb = (B_OFF + rB + (cc0 ^ 32)) * 2;
    const char* const ldsc = (const char*)lds;

    f32x4 acc[2][2][4][2] = {};
    bf16x8 afLo[4][2], afHi[4][2];   // [j][ks]
    bf16x8 bf0[2][2], bf1[2][2];     // [j2][ks]

    auto rd_afLo_next = [&]() {   // A half0 of NEXT tile (other slot)
        const int xa = oAa ^ SLOT_BYTES, xb2 = oAb ^ SLOT_BYTES;
        #pragma unroll
        for (int j = 0; j < 4; ++j) {
            afLo[j][0] = *(const bf16x8*)(ldsc + xa + j * 4096);
            afLo[j][1] = *(const bf16x8*)(ldsc + xb2 + j * 4096);
        }
    };
    auto rd_bf0_next = [&]() {    // B half0 of NEXT tile (other slot)
        const int xa = oBa ^ SLOT_BYTES, xb2 = oBb ^ SLOT_BYTES;
        #pragma unroll
        for (int j2 = 0; j2 < 2; ++j2) {
            bf0[j2][0] = *(const bf16x8*)(ldsc + xa + j2 * 8192);
            bf0[j2][1] = *(const bf16x8*)(ldsc + xb2 + j2 * 8192);
        }
    };
    auto rd_afHi_cur = [&]() {    // A half1 of CURRENT tile
        #pragma unroll
        for (int j = 0; j < 4; ++j) {
            afHi[j][0] = *(const bf16x8*)(ldsc + oAa + 16384 + j * 4096);
            afHi[j][1] = *(const bf16x8*)(ldsc + oAb + 16384 + j * 4096);
        }
    };
    auto rd_bf1_cur = [&]() {     // B half1 of CURRENT tile
        #pragma unroll
        for (int j2 = 0; j2 < 2; ++j2) {
            bf1[j2][0] = *(const bf16x8*)(ldsc + oBa + 16384 + j2 * 8192);
            bf1[j2][1] = *(const bf16x8*)(ldsc + oBb + 16384 + j2 * 8192);
        }
    };

    #define MFMA_CLUSTER(A, B, MH, NH)                                          \
        __builtin_amdgcn_s_setprio(1);                                          \
        _Pragma("unroll")                                                       \
        for (int ks = 0; ks < 2; ++ks)                                          \
            _Pragma("unroll")                                                   \
            for (int j = 0; j < 4; ++j)                                         \
                _Pragma("unroll")                                               \
                for (int j2 = 0; j2 < 2; ++j2)                                  \
                    acc[MH][NH][j][j2] = __builtin_amdgcn_mfma_f32_16x16x32_bf16(\
                        A[j][ks], B[j2][ks], acc[MH][NH][j][j2], 0, 0, 0);      \
        __builtin_amdgcn_s_setprio(0);

    // one K-tile. Stg: stage tile t+2 -> S (A0B0 @p1, A1B1 @p3), delta D.
    // RdN: one-ahead frag reads of t+1. V1/V3: counted vmcnt (-1 = skip).
    auto ktile = [&](auto SlC, auto Stg, auto RdN, auto V1c, auto V3c, auto Dc) {
        constexpr int SL = SlC.value;
        // ---- p0 ----
        rd_bf1_cur();
        MFMA_CLUSTER(afLo, bf0, 0, 0)
        // ---- p1 ----
        rd_afHi_cur();
        if constexpr (Stg.value) { stA(SlC, ic<0>{}, Dc);
                                   stB(SlC, ic<0>{}, Dc); }
        MFMA_CLUSTER(afLo, bf1, 0, 1)
        if constexpr (V1c.value == 8) asm volatile("s_waitcnt vmcnt(8)" ::: "memory");
        else if constexpr (V1c.value == 4) asm volatile("s_waitcnt vmcnt(4)" ::: "memory");
        __builtin_amdgcn_s_barrier();
        __builtin_amdgcn_sched_barrier(0);
        // ---- p2 ----
        if constexpr (RdN.value) rd_afLo_next();
        MFMA_CLUSTER(afHi, bf1, 1, 1)
        // ---- p3 ----
        MFMA_CLUSTER(afHi, bf0, 1, 0)
        if constexpr (RdN.value) rd_bf0_next();
        if constexpr (Stg.value) { stA(SlC, ic<1>{}, Dc);
                                   stB(SlC, ic<1>{}, Dc); }
        if constexpr (V3c.value == 8) asm volatile("s_waitcnt vmcnt(8)" ::: "memory");
        else if constexpr (V3c.value == 0) asm volatile("s_waitcnt vmcnt(0)" ::: "memory");
        __builtin_amdgcn_s_barrier();
        __builtin_amdgcn_sched_barrier(0);
        // toggle read bases to the other slot
        oAa ^= SLOT_BYTES; oAb ^= SLOT_BYTES; oBa ^= SLOT_BYTES; oBb ^= SLOT_BYTES;
    };

    // prologue: stage tile0 (8) then tile1 (8, stays in flight = the steady
    // residue {A0B0(t+1),A1B1(t+1)}); vmcnt(8) drains tile0; barrier; read
    // tile0's q0 fragments.
    stA(ic<0>{}, ic<0>{}, ic<0>{});  stB(ic<0>{}, ic<0>{}, ic<0>{});
    stA(ic<0>{}, ic<1>{}, ic<0>{});  stB(ic<0>{}, ic<1>{}, ic<0>{});
    stA(ic<1>{}, ic<0>{}, ic<BK>{}); stB(ic<1>{}, ic<0>{}, ic<BK>{});
    stA(ic<1>{}, ic<1>{}, ic<BK>{}); stB(ic<1>{}, ic<1>{}, ic<BK>{});
    asm volatile("s_waitcnt vmcnt(8)" ::: "memory");
    __builtin_amdgcn_s_barrier();
    __builtin_amdgcn_sched_barrier(0);
    {   // initial q0 fragments from slot 0 (bases currently at slot 0)
        #pragma unroll
        for (int j = 0; j < 4; ++j) {
            afLo[j][0] = *(const bf16x8*)(ldsc + oAa + j * 4096);
            afLo[j][1] = *(const bf16x8*)(ldsc + oAb + j * 4096);
        }
        #pragma unroll
        for (int j2 = 0; j2 < 2; ++j2) {
            bf0[j2][0] = *(const bf16x8*)(ldsc + oBa + j2 * 8192);
            bf0[j2][1] = *(const bf16x8*)(ldsc + oBb + j2 * 8192);
        }
    }

    // steady: 31 pairs = tiles 0..61; tile t stages t+2 (slot0: +2BK, slot1: +3BK)
    for (int it = 0; it < 31; ++it) {
        ktile(ic<0>{}, bc<true>{}, bc<true>{}, ic<8>{}, ic<8>{}, ic<2 * BK>{});
        ktile(ic<1>{}, bc<true>{}, bc<true>{}, ic<8>{}, ic<8>{}, ic<3 * BK>{});
        aT += 2 * BK;
        bT += 2 * BK;
    }
    // tile 62: no staging (t+2=64); V1=4 drains A0B0(63) [61.p1], leaves
    // A1B1(63); V3=0 drains A1B1(63) [61.p3] for tile 63's reads.
    ktile(ic<0>{}, bc<false>{}, bc<true>{}, ic<4>{}, ic<0>{}, ic<0>{});
    // tile 63: no stages, no ahead-reads, pipe clean
    ktile(ic<1>{}, bc<false>{}, bc<false>{}, ic<-1>{}, ic<-1>{}, ic<0>{});

    #undef MFMA_CLUSTER

    // epilogue: C/D layout col = lane&15 (out-dim), row = (lane>>4)*4 + rr (M)
    #pragma unroll
    for (int mh_ = 0; mh_ < 2; ++mh_)
        #pragma unroll
        for (int j = 0; j < 4; ++j)
            #pragma unroll
            for (int rr = 0; rr < 4; ++rr) {
                const int row = bm * BM + mh_ * 128 + j * 32 + wm * 16 + ((lane >> 4) << 2) + rr;
                float* orow = out + (size_t)row * K_TOT;
                #pragma unroll
                for (int nh_ = 0; nh_ < 2; ++nh_)
                    #pragma unroll
                    for (int j2 = 0; j2 < 2; ++j2) {
                        const int col = bn * BN + nh_ * 128 + j2 * 64 + wn * 16 + (lane & 15);
                        orow[col] = acc[mh_][nh_][j][j2][rr] + bias[col];
                    }
            }
}

extern "C" void kernel_launch(void* const* d_in, const int* in_sizes, int n_in,
                              void* d_out, int out_size, void* d_ws, size_t ws_size,
                              hipStream_t stream) {
    const float* x      = (const float*)d_in[0];
    const float* scales = (const float*)d_in[1];
    const float* zeros  = (const float*)d_in[2];
    const float* mu1    = (const float*)d_in[3];
    const float* mu2    = (const float*)d_in[4];
    const float* bias   = (const float*)d_in[5];
    const int*   wq     = (const int*)d_in[6];
    float* out = (float*)d_out;

    u16* xb = (u16*)d_ws;                                 // 64 MiB
    u16* wb = (u16*)d_ws + (size_t)M_TOT * N_TOT;         // 32 MiB

    prep_kernel<<<CVT_BLOCKS + DEQ_BLOCKS, 256, 0, stream>>>(
        x, xb, wq, scales, zeros, mu1, mu2, wb);
    gemm_kernel<<<(M_TOT / BM) * (K_TOT / BN), 512, 0, stream>>>(xb, wb, bias, out);
}